// Round 9
// baseline (421.363 us; speedup 1.0000x reference)
//
#include <hip/hip_runtime.h>

// ---- problem constants (from reference) ----
#define NB 2
#define NT 3
#define NCAM 6
#define NC 16
#define FD 48
#define FH 24
#define FW 64
#define GX 100
#define GY 100
#define GZ 8
#define OC 40
#define NVOX (GX * GY * GZ)          // 80000  (divisible by 64 -> bt, b wave-uniform)
#define FSZ (FD * FH * FW)           // 73728 voxels per channel volume
#define CAMSZ (NC * FSZ)             // per-camera feature volume (orig layout)
#define BTSZ (NCAM * CAMSZ)          // per-(b,t) feature block (orig layout)
#define HSZ ((size_t)NB * NT * OC * NVOX)             // 19,200,000 elems
#define FT_ELEMS ((size_t)NB * NT * NCAM * FSZ * NC)  // 42,467,328

static __device__ __forceinline__ unsigned short f2bf_rne(float x) {
    unsigned int u = __float_as_uint(x);
    unsigned int r = (u + 0x7fffu + ((u >> 16) & 1u)) >> 16;
    return (unsigned short)r;
}
static __device__ __forceinline__ float bf_lo(unsigned int u) {
    return __uint_as_float(u << 16);
}
static __device__ __forceinline__ float bf_hi(unsigned int u) {
    return __uint_as_float(u & 0xffff0000u);
}

// Bijective XCD-aware block swizzle (contiguous chunk per XCD; m204 form).
// warp_mlp2 only (R5: FETCH 75->20 MB there).
static __device__ __forceinline__ int xcd_swizzle(int bid, int nwg) {
    int xcd = bid & 7;
    int local = bid >> 3;
    int q = nwg >> 3, r = nwg & 7;
    return (xcd < r ? xcd * (q + 1) : r * (q + 1) + (xcd - r) * q) + local;
}

// ----------------------------------------------------------------------------
// Setup: P[b,t,n] = intrins[b] @ RT[b,t,n][:3,:]  (3x4)
//        theta[b,t] cumulative affine; t=2 -> I
//        g_const[b,t][40] = bf16( W_T[:, t*40:(t+1)*40] @ relu(b_N) )
//        (the sample epilogue output for voxels seen by NO camera)
// ----------------------------------------------------------------------------
static __device__ __forceinline__ void do_setup(
    int tid, const float* __restrict__ RT, const float* __restrict__ intrins,
    const float* __restrict__ DoF, const float* __restrict__ W_T,
    const float* __restrict__ b_N, float* __restrict__ P,
    float* __restrict__ theta, unsigned short* __restrict__ g_const) {
    if (tid < NB * NT * NCAM) {
        int bt = tid / NCAM;
        int b = bt / NT;
        const float* I3 = intrins + b * 9;
        const float* R = RT + (size_t)tid * 16;
        float* Pp = P + tid * 12;
        for (int r = 0; r < 3; ++r)
            for (int c = 0; c < 4; ++c) {
                float s = 0.f;
                for (int k = 0; k < 3; ++k) s += I3[r * 3 + k] * R[k * 4 + c];
                Pp[r * 4 + c] = s;
            }
    }
    if (tid >= 64 && tid < 64 + NB) {
        int b = tid - 64;
        const float* D0 = DoF + (size_t)(b * NT + 0) * 16;
        const float* D1 = DoF + (size_t)(b * NT + 1) * 16;
        float* th = theta + (size_t)b * NT * 12;
        for (int i = 0; i < 12; ++i) th[2 * 12 + i] = 0.f;
        th[2 * 12 + 0] = 1.f; th[2 * 12 + 5] = 1.f; th[2 * 12 + 10] = 1.f;
        for (int i = 0; i < 12; ++i) th[1 * 12 + i] = D1[i];
        for (int r = 0; r < 3; ++r)
            for (int c = 0; c < 4; ++c) {
                float s = (c == 3) ? D0[r * 4 + 3] : 0.f;
                for (int k = 0; k < 3; ++k) s += D0[r * 4 + k] * D1[k * 4 + c];
                th[0 * 12 + r * 4 + c] = s;
            }
    }
    if (tid >= 96 && tid < 96 + NB * NT) {
        int bt = tid - 96;
        int t = bt % NT;
        unsigned short* gc = g_const + (size_t)bt * OC;
        for (int o = 0; o < OC; ++o) {
            float s = 0.f;
            const float* wrow = W_T + (size_t)o * (NT * OC) + t * OC;
            for (int c = 0; c < OC; ++c) s += wrow[c] * fmaxf(b_N[c], 0.f);
            gc[o] = f2bf_rne(s);
        }
    }
}

__global__ void setup_kernel(const float* __restrict__ RT,
                             const float* __restrict__ intrins,
                             const float* __restrict__ DoF,
                             const float* __restrict__ W_T,
                             const float* __restrict__ b_N,
                             float* __restrict__ P,
                             float* __restrict__ theta,
                             unsigned short* __restrict__ g_const) {
    do_setup(threadIdx.x, RT, intrins, DoF, W_T, b_N, P, theta, g_const);
}

// ----------------------------------------------------------------------------
// Transpose features (B,T,N,C,FD,FH,FW) fp32 -> [btn][pos][C16] bf16.
// VECTORIZED (R9): 4 consecutive pos per thread -> 16 float4 loads
// (16B/lane = 1KB/instruction, the coalescing sweet spot; the old scalar
// version issued 4x the load instructions at 256B each and sat at 20% HBM
// with VALUBusy 5.7%). Register 4x16 micro-transpose, 128B contiguous store.
// Block 0 additionally performs setup (fused dispatch).
// ----------------------------------------------------------------------------
__global__ __launch_bounds__(256) void transpose_feat(
    const float* __restrict__ feat, unsigned short* __restrict__ ft,
    const float* __restrict__ RT, const float* __restrict__ intrins,
    const float* __restrict__ DoF, const float* __restrict__ W_T,
    const float* __restrict__ b_N, float* __restrict__ P,
    float* __restrict__ theta, unsigned short* __restrict__ g_const) {
    if (blockIdx.x == 0)
        do_setup(threadIdx.x, RT, intrins, DoF, W_T, b_N, P, theta, g_const);
    int idx = blockIdx.x * 256 + threadIdx.x;
    int pos4 = idx % (FSZ / 4);
    int btn = idx / (FSZ / 4);
    int pos = pos4 * 4;
    const float* src = feat + (size_t)btn * CAMSZ + pos;

    float4 v[NC];
#pragma unroll
    for (int c = 0; c < NC; ++c)
        v[c] = *reinterpret_cast<const float4*>(src + (size_t)c * FSZ);

    uint4* dst = reinterpret_cast<uint4*>(ft + ((size_t)btn * FSZ + pos) * NC);

#define PACK_POS(P, FIELD)                                                   \
    {                                                                        \
        unsigned int pk[8];                                                  \
        _Pragma("unroll") for (int j = 0; j < 8; ++j) pk[j] =                \
            (unsigned int)f2bf_rne(v[2 * j].FIELD) |                         \
            ((unsigned int)f2bf_rne(v[2 * j + 1].FIELD) << 16);              \
        dst[2 * P + 0] = make_uint4(pk[0], pk[1], pk[2], pk[3]);             \
        dst[2 * P + 1] = make_uint4(pk[4], pk[5], pk[6], pk[7]);             \
    }
    PACK_POS(0, x)
    PACK_POS(1, y)
    PACK_POS(2, z)
    PACK_POS(3, w)
#undef PACK_POS
}

// ----------------------------------------------------------------------------
// Kernel 1: frustum trilinear sample (6 cams x 16 ch) + W_N matvec + ReLU,
// + hoisted W_T-block matvec: store g_t = W_T[:, t*40:] @ relu(h)  (bf16).
// bf16 ft gather (2 x uint4 = 32B/corner). Per-cam validity early-out.
// Light-thread shortcut: no valid cam -> constant g row from setup.
// Unchanged from R8.
// ----------------------------------------------------------------------------
template <bool CHLAST>
__global__ __launch_bounds__(256) void sample_mlp1(
    const float* __restrict__ feat,            // original layout (!CHLAST)
    const unsigned short* __restrict__ ft,     // bf16 channel-last (CHLAST)
    const float* __restrict__ P,
    const float* __restrict__ W_N,
    const float* __restrict__ b_N,
    const float* __restrict__ W_T,
    const unsigned short* __restrict__ g_const,
    unsigned short* __restrict__ g) {
    int tid = blockIdx.x * 256 + threadIdx.x;
    int vid = tid % NVOX;
    int bt = __builtin_amdgcn_readfirstlane(tid / NVOX);  // wave-uniform (NVOX%64==0)
    int gy = vid % GY;
    int r2 = vid / GY;
    int gz = r2 % GZ;
    int gx = r2 / GZ;
    float X = (float)gx - 49.5f;
    float Y = (float)gy - 49.5f;
    float Z = (float)gz - 2.5f;

    uint4* d4 = reinterpret_cast<uint4*>(
        g + ((size_t)bt * NVOX + (size_t)vid) * OC);

    float acc[OC];
#pragma unroll
    for (int o = 0; o < OC; ++o) acc[o] = b_N[o];

    bool any_valid = false;

    for (int n = 0; n < NCAM; ++n) {
        const float* Pp = P + (bt * NCAM + n) * 12;
        float px = Pp[0] * X + Pp[1] * Y + Pp[2] * Z + Pp[3];
        float py = Pp[4] * X + Pp[5] * Y + Pp[6] * Z + Pp[7];
        float pz = Pp[8] * X + Pp[9] * Y + Pp[10] * Z + Pp[11];
        float zc = fmaxf(pz, 1e-5f);
        float ix = px / zc;                       // = u (normalization round-trips)
        float iy = py / zc;
        float iz = (pz - 2.0f) * (48.0f / 44.8f); // = dbin

        // exact early-out: outside the open box, every corner weight is zero
        bool cam_valid = (ix > -1.f) & (ix < (float)FW) &
                         (iy > -1.f) & (iy < (float)FH) &
                         (iz > -1.f) & (iz < (float)FD);
        if (!cam_valid) continue;
        any_valid = true;

        float x0 = floorf(ix), y0 = floorf(iy), z0 = floorf(iz);
        float wx1 = ix - x0, wy1 = iy - y0, wz1 = iz - z0;
        float wx0 = 1.f - wx1, wy0 = 1.f - wy1, wz0 = 1.f - wz1;

        float w8[8];
        int off8[8];
#pragma unroll
        for (int k = 0; k < 8; ++k) {
            float xf = x0 + (float)(k & 1);
            float yf = y0 + (float)((k >> 1) & 1);
            float zf = z0 + (float)(k >> 2);
            bool valid = (xf >= 0.f) & (xf <= (float)(FW - 1)) &
                         (yf >= 0.f) & (yf <= (float)(FH - 1)) &
                         (zf >= 0.f) & (zf <= (float)(FD - 1));
            int xi = (int)fminf(fmaxf(xf, 0.f), (float)(FW - 1));
            int yi = (int)fminf(fmaxf(yf, 0.f), (float)(FH - 1));
            int zi = (int)fminf(fmaxf(zf, 0.f), (float)(FD - 1));
            float w = ((k & 1) ? wx1 : wx0) * (((k >> 1) & 1) ? wy1 : wy0) *
                      ((k >> 2) ? wz1 : wz0);
            w8[k] = valid ? w : 0.f;
            off8[k] = (zi * FH + yi) * FW + xi;
        }

        float s[NC];
#pragma unroll
        for (int c = 0; c < NC; ++c) s[c] = 0.f;

        if constexpr (CHLAST) {
            const size_t camBase = (size_t)(bt * NCAM + n) * FSZ;
#pragma unroll
            for (int k = 0; k < 8; ++k) {
                float w = w8[k];
                const uint4* cp = reinterpret_cast<const uint4*>(
                    ft + (camBase + (size_t)off8[k]) * NC);
                uint4 a = cp[0], b2 = cp[1];
                unsigned int uu[8] = {a.x, a.y, a.z, a.w, b2.x, b2.y, b2.z, b2.w};
#pragma unroll
                for (int j = 0; j < 8; ++j) {
                    s[2 * j + 0] = fmaf(w, bf_lo(uu[j]), s[2 * j + 0]);
                    s[2 * j + 1] = fmaf(w, bf_hi(uu[j]), s[2 * j + 1]);
                }
            }
        } else {
            const float* fn = feat + (size_t)bt * BTSZ + (size_t)n * CAMSZ;
#pragma unroll
            for (int c = 0; c < NC; ++c) {
                const float* fc = fn + (size_t)c * FSZ;
                float v = 0.f;
#pragma unroll
                for (int k = 0; k < 8; ++k) v = fmaf(w8[k], fc[off8[k]], v);
                s[c] = v;
            }
        }

        // acc[o] += W_N[o, n*16 + c] * s[c]
#pragma unroll
        for (int o = 0; o < OC; ++o) {
            const float4* w4 =
                reinterpret_cast<const float4*>(W_N + o * (NCAM * NC) + n * NC);
#pragma unroll
            for (int q = 0; q < 4; ++q) {
                float4 w = w4[q];
                acc[o] = fmaf(w.x, s[4 * q + 0], acc[o]);
                acc[o] = fmaf(w.y, s[4 * q + 1], acc[o]);
                acc[o] = fmaf(w.z, s[4 * q + 2], acc[o]);
                acc[o] = fmaf(w.w, s[4 * q + 3], acc[o]);
            }
        }
    }

    // ---- light-thread shortcut: no cam saw this voxel -> constant g row ----
    if (!any_valid) {
        const uint4* gc = reinterpret_cast<const uint4*>(
            g_const + (size_t)bt * OC);
        uint4 r0 = gc[0], r1 = gc[1], r2_ = gc[2], r3 = gc[3], r4 = gc[4];
        d4[0] = r0; d4[1] = r1; d4[2] = r2_; d4[3] = r3; d4[4] = r4;
        return;
    }

    // ReLU (this is h), then hoisted W_T-block matvec: g = W_T[:, t*40:] @ h.
    // 8 outputs at a time to keep the live set small (R4 spill lesson).
#pragma unroll
    for (int o = 0; o < OC; ++o) acc[o] = fmaxf(acc[o], 0.f);

    const int t = bt % NT;  // wave-uniform
    const float* Wtb = W_T + t * OC;            // row o at Wtb + o*(NT*OC)
#pragma unroll
    for (int grp = 0; grp < 5; ++grp) {
        float g8[8];
#pragma unroll
        for (int j = 0; j < 8; ++j) {
            const float4* w4 = reinterpret_cast<const float4*>(
                Wtb + (size_t)(grp * 8 + j) * (NT * OC));
            float s0 = 0.f;
#pragma unroll
            for (int q = 0; q < 10; ++q) {
                float4 w = w4[q];
                s0 = fmaf(w.x, acc[4 * q + 0], s0);
                s0 = fmaf(w.y, acc[4 * q + 1], s0);
                s0 = fmaf(w.z, acc[4 * q + 2], s0);
                s0 = fmaf(w.w, acc[4 * q + 3], s0);
            }
            g8[j] = s0;
        }
        unsigned int u0 = (unsigned int)f2bf_rne(g8[0]) |
                          ((unsigned int)f2bf_rne(g8[1]) << 16);
        unsigned int u1 = (unsigned int)f2bf_rne(g8[2]) |
                          ((unsigned int)f2bf_rne(g8[3]) << 16);
        unsigned int u2 = (unsigned int)f2bf_rne(g8[4]) |
                          ((unsigned int)f2bf_rne(g8[5]) << 16);
        unsigned int u3 = (unsigned int)f2bf_rne(g8[6]) |
                          ((unsigned int)f2bf_rne(g8[7]) << 16);
        d4[grp] = make_uint4(u0, u1, u2, u3);
    }
}

// ----------------------------------------------------------------------------
// Kernel 2: temporal warp, post-hoist: out = relu(gather_t0(g0) + gather_t1(g1)
// + g2[vid] + b_T). t=2 theta == I -> exact pass-through (single 80B load).
// Unchanged from R7. out layout: [b][o][d][h][w] = (B,40,100,8,100)
// ----------------------------------------------------------------------------
__global__ __launch_bounds__(256) void warp_mlp2(
    const unsigned short* __restrict__ g,
    const float* __restrict__ theta,
    const float* __restrict__ b_T,
    float* __restrict__ out) {
    int bid = xcd_swizzle(blockIdx.x, gridDim.x);
    int tid = bid * 256 + threadIdx.x;
    int vid = tid % NVOX;
    int b = __builtin_amdgcn_readfirstlane(tid / NVOX);  // wave-uniform
    int w_ = vid % GY;        // Wp = 100
    int r2 = vid / GY;
    int h_ = r2 % GZ;         // Hp = 8
    int d_ = r2 / GZ;         // Dp = 100

    float xg = -1.f + 2.f * (float)w_ / 99.f;
    float yg = -1.f + 2.f * (float)h_ / 7.f;
    float zg = -1.f + 2.f * (float)d_ / 99.f;

    float sval[OC];
#pragma unroll
    for (int o = 0; o < OC; ++o) sval[o] = b_T[o];

    // ---- t = 0, 1: trilinear gather of g_t, accumulated into sval ----
    for (int t = 0; t < 2; ++t) {
        const float* th = theta + (b * NT + t) * 12;
        float g0 = th[0] * xg + th[1] * yg + th[2] * zg + th[3];
        float g1 = th[4] * xg + th[5] * yg + th[6] * zg + th[7];
        float g2 = th[8] * xg + th[9] * yg + th[10] * zg + th[11];
        float ix = (g0 + 1.f) * 0.5f * 99.f;
        float iy = (g1 + 1.f) * 0.5f * 7.f;
        float iz = (g2 + 1.f) * 0.5f * 99.f;
        float x0 = floorf(ix), y0 = floorf(iy), z0 = floorf(iz);
        float wx1 = ix - x0, wy1 = iy - y0, wz1 = iz - z0;
        float wx0 = 1.f - wx1, wy0 = 1.f - wy1, wz0 = 1.f - wz1;

        float w8[8];
        int off8[8];
#pragma unroll
        for (int k = 0; k < 8; ++k) {
            float xf = x0 + (float)(k & 1);
            float yf = y0 + (float)((k >> 1) & 1);
            float zf = z0 + (float)(k >> 2);
            bool valid = (xf >= 0.f) & (xf <= 99.f) &
                         (yf >= 0.f) & (yf <= 7.f) &
                         (zf >= 0.f) & (zf <= 99.f);
            int xi = (int)fminf(fmaxf(xf, 0.f), 99.f);
            int yi = (int)fminf(fmaxf(yf, 0.f), 7.f);
            int zi = (int)fminf(fmaxf(zf, 0.f), 99.f);
            float w = ((k & 1) ? wx1 : wx0) * (((k >> 1) & 1) ? wy1 : wy0) *
                      ((k >> 2) ? wz1 : wz0);
            w8[k] = valid ? w : 0.f;
            off8[k] = (zi * GZ + yi) * GY + xi;  // voxel index in [vid] space
        }

        const unsigned short* hb = g + (size_t)(b * NT + t) * NVOX * OC;
#pragma unroll
        for (int k = 0; k < 8; ++k) {
            float w = w8[k];
            const uint4* cp =
                reinterpret_cast<const uint4*>(hb + (size_t)off8[k] * OC);
            uint4 a0 = cp[0], a1 = cp[1], a2 = cp[2], a3 = cp[3], a4 = cp[4];
            unsigned int uu[20] = {a0.x, a0.y, a0.z, a0.w, a1.x, a1.y, a1.z, a1.w,
                                   a2.x, a2.y, a2.z, a2.w, a3.x, a3.y, a3.z, a3.w,
                                   a4.x, a4.y, a4.z, a4.w};
#pragma unroll
            for (int j = 0; j < 20; ++j) {
                sval[2 * j + 0] = fmaf(w, bf_lo(uu[j]), sval[2 * j + 0]);
                sval[2 * j + 1] = fmaf(w, bf_hi(uu[j]), sval[2 * j + 1]);
            }
        }
    }

    // ---- t = 2: identity grid -> exact pass-through (single 80B load) ----
    {
        const uint4* cp = reinterpret_cast<const uint4*>(
            g + ((size_t)(b * NT + 2) * NVOX + (size_t)vid) * OC);
        uint4 a0 = cp[0], a1 = cp[1], a2 = cp[2], a3 = cp[3], a4 = cp[4];
        unsigned int uu[20] = {a0.x, a0.y, a0.z, a0.w, a1.x, a1.y, a1.z, a1.w,
                               a2.x, a2.y, a2.z, a2.w, a3.x, a3.y, a3.z, a3.w,
                               a4.x, a4.y, a4.z, a4.w};
#pragma unroll
        for (int j = 0; j < 20; ++j) {
            sval[2 * j + 0] += bf_lo(uu[j]);
            sval[2 * j + 1] += bf_hi(uu[j]);
        }
    }

    // per-o planes: lanes have consecutive vid -> coalesced per o
    float* op = out + (size_t)b * OC * NVOX + vid;
#pragma unroll
    for (int o = 0; o < OC; ++o) op[(size_t)o * NVOX] = fmaxf(sval[o], 0.f);
}

extern "C" void kernel_launch(void* const* d_in, const int* in_sizes, int n_in,
                              void* d_out, int out_size, void* d_ws, size_t ws_size,
                              hipStream_t stream) {
    const float* frustum = (const float*)d_in[0];
    const float* RT      = (const float*)d_in[1];
    const float* intrins = (const float*)d_in[2];
    const float* DoF     = (const float*)d_in[3];
    const float* W_N     = (const float*)d_in[4];
    const float* b_N     = (const float*)d_in[5];
    const float* W_T     = (const float*)d_in[6];
    const float* b_T     = (const float*)d_in[7];
    float* out = (float*)d_out;

    const size_t ft_bytes = FT_ELEMS * sizeof(unsigned short); // ~85 MB
    const size_t g_bytes  = HSZ * sizeof(unsigned short);      // ~38.4 MB
    const size_t small = 4096;                                 // P + theta + g_const

    char* base = (char*)d_ws;
    bool use_ft = ws_size >= ft_bytes + g_bytes + small;

    size_t ft_al = use_ft ? ((ft_bytes + 255) & ~(size_t)255) : 0;
    unsigned short* ft_buf = (unsigned short*)base;
    unsigned short* g_buf = (unsigned short*)(base + ft_al);
    float* P_buf = (float*)(base + ft_al + ((g_bytes + 255) & ~(size_t)255));
    float* th_buf = P_buf + NB * NT * NCAM * 12;              // 432 floats in
    unsigned short* gc_buf = (unsigned short*)(th_buf + NB * NT * 12);

    const int tr_blocks = (NB * NT * NCAM * FSZ / 4) / 256;  // 2592
    const int n1_blocks = (NB * NT * NVOX) / 256;            // 1875
    const int n2_blocks = (NB * NVOX) / 256;                 // 625

    if (use_ft) {
        transpose_feat<<<tr_blocks, 256, 0, stream>>>(
            frustum, ft_buf, RT, intrins, DoF, W_T, b_N, P_buf, th_buf, gc_buf);
        sample_mlp1<true><<<n1_blocks, 256, 0, stream>>>(
            frustum, ft_buf, P_buf, W_N, b_N, W_T, gc_buf, g_buf);
    } else {
        setup_kernel<<<1, 128, 0, stream>>>(
            RT, intrins, DoF, W_T, b_N, P_buf, th_buf, gc_buf);
        sample_mlp1<false><<<n1_blocks, 256, 0, stream>>>(
            frustum, (const unsigned short*)nullptr, P_buf, W_N, b_N, W_T,
            gc_buf, g_buf);
    }

    warp_mlp2<<<n2_blocks, 256, 0, stream>>>(g_buf, th_buf, b_T, out);
}

// Round 10
// 393.570 us; speedup vs baseline: 1.0706x; 1.0706x over previous
//
#include <hip/hip_runtime.h>

// ---- problem constants (from reference) ----
#define NB 2
#define NT 3
#define NCAM 6
#define NC 16
#define FD 48
#define FH 24
#define FW 64
#define GX 100
#define GY 100
#define GZ 8
#define OC 40
#define NVOX (GX * GY * GZ)          // 80000  (divisible by 64 -> bt, b wave-uniform)
#define FSZ (FD * FH * FW)           // 73728 voxels per channel volume
#define CAMSZ (NC * FSZ)             // per-camera feature volume (orig layout)
#define BTSZ (NCAM * CAMSZ)          // per-(b,t) feature block (orig layout)
#define HSZ ((size_t)NB * NT * OC * NVOX)             // 19,200,000 elems
#define FT_ELEMS ((size_t)NB * NT * NCAM * FSZ * NC)  // 42,467,328
#define TR_TILE 1024                 // pos per transpose block (FSZ/1024 = 72)

static __device__ __forceinline__ unsigned short f2bf_rne(float x) {
    unsigned int u = __float_as_uint(x);
    unsigned int r = (u + 0x7fffu + ((u >> 16) & 1u)) >> 16;
    return (unsigned short)r;
}
static __device__ __forceinline__ float bf_lo(unsigned int u) {
    return __uint_as_float(u << 16);
}
static __device__ __forceinline__ float bf_hi(unsigned int u) {
    return __uint_as_float(u & 0xffff0000u);
}

// Bijective XCD-aware block swizzle (contiguous chunk per XCD; m204 form).
// warp_mlp2 only (R5: FETCH 75->20 MB there).
static __device__ __forceinline__ int xcd_swizzle(int bid, int nwg) {
    int xcd = bid & 7;
    int local = bid >> 3;
    int q = nwg >> 3, r = nwg & 7;
    return (xcd < r ? xcd * (q + 1) : r * (q + 1) + (xcd - r) * q) + local;
}

// ----------------------------------------------------------------------------
// Setup: P[b,t,n] = intrins[b] @ RT[b,t,n][:3,:]  (3x4)
//        theta[b,t] cumulative affine; t=2 -> I
//        g_const[b,t][40] = bf16( W_T[:, t*40:(t+1)*40] @ relu(b_N) )
// ----------------------------------------------------------------------------
static __device__ __forceinline__ void do_setup(
    int tid, const float* __restrict__ RT, const float* __restrict__ intrins,
    const float* __restrict__ DoF, const float* __restrict__ W_T,
    const float* __restrict__ b_N, float* __restrict__ P,
    float* __restrict__ theta, unsigned short* __restrict__ g_const) {
    if (tid < NB * NT * NCAM) {
        int bt = tid / NCAM;
        int b = bt / NT;
        const float* I3 = intrins + b * 9;
        const float* R = RT + (size_t)tid * 16;
        float* Pp = P + tid * 12;
        for (int r = 0; r < 3; ++r)
            for (int c = 0; c < 4; ++c) {
                float s = 0.f;
                for (int k = 0; k < 3; ++k) s += I3[r * 3 + k] * R[k * 4 + c];
                Pp[r * 4 + c] = s;
            }
    }
    if (tid >= 64 && tid < 64 + NB) {
        int b = tid - 64;
        const float* D0 = DoF + (size_t)(b * NT + 0) * 16;
        const float* D1 = DoF + (size_t)(b * NT + 1) * 16;
        float* th = theta + (size_t)b * NT * 12;
        for (int i = 0; i < 12; ++i) th[2 * 12 + i] = 0.f;
        th[2 * 12 + 0] = 1.f; th[2 * 12 + 5] = 1.f; th[2 * 12 + 10] = 1.f;
        for (int i = 0; i < 12; ++i) th[1 * 12 + i] = D1[i];
        for (int r = 0; r < 3; ++r)
            for (int c = 0; c < 4; ++c) {
                float s = (c == 3) ? D0[r * 4 + 3] : 0.f;
                for (int k = 0; k < 3; ++k) s += D0[r * 4 + k] * D1[k * 4 + c];
                th[0 * 12 + r * 4 + c] = s;
            }
    }
    if (tid >= 96 && tid < 96 + NB * NT) {
        int bt = tid - 96;
        int t = bt % NT;
        unsigned short* gc = g_const + (size_t)bt * OC;
        for (int o = 0; o < OC; ++o) {
            float s = 0.f;
            const float* wrow = W_T + (size_t)o * (NT * OC) + t * OC;
            for (int c = 0; c < OC; ++c) s += wrow[c] * fmaxf(b_N[c], 0.f);
            gc[o] = f2bf_rne(s);
        }
    }
}

__global__ void setup_kernel(const float* __restrict__ RT,
                             const float* __restrict__ intrins,
                             const float* __restrict__ DoF,
                             const float* __restrict__ W_T,
                             const float* __restrict__ b_N,
                             float* __restrict__ P,
                             float* __restrict__ theta,
                             unsigned short* __restrict__ g_const) {
    do_setup(threadIdx.x, RT, intrins, DoF, W_T, b_N, P, theta, g_const);
}

// ----------------------------------------------------------------------------
// Transpose features (B,T,N,C,FD,FH,FW) fp32 -> [btn][pos][C16] bf16.
// R10: LDS-EXCHANGE. R9's direct 4-pos/thread version had contiguous-per-
// THREAD but 128B-lane-stride stores -> partial-cacheline write amplification
// (WRITE 83->98.5 MB, dur 106->135). This version keeps the 1KB/instr float4
// reads (phase 1) and makes stores lane-contiguous via a 32KB LDS tile
// (phase 2: byte addr = s*4096 + tid*16 -> zero amplification).
// Block 0 additionally performs setup (fused dispatch).
// ----------------------------------------------------------------------------
__global__ __launch_bounds__(256) void transpose_feat(
    const float* __restrict__ feat, unsigned short* __restrict__ ft,
    const float* __restrict__ RT, const float* __restrict__ intrins,
    const float* __restrict__ DoF, const float* __restrict__ W_T,
    const float* __restrict__ b_N, float* __restrict__ P,
    float* __restrict__ theta, unsigned short* __restrict__ g_const) {
    __shared__ unsigned short lds[NC * TR_TILE];   // 32 KB, layout [c][pos]
    if (blockIdx.x == 0)
        do_setup(threadIdx.x, RT, intrins, DoF, W_T, b_N, P, theta, g_const);

    int tid = threadIdx.x;
    int tile = blockIdx.x % (FSZ / TR_TILE);       // 72 tiles per btn
    int btn = blockIdx.x / (FSZ / TR_TILE);
    int base = tile * TR_TILE;
    const float* src = feat + (size_t)btn * CAMSZ + base;

    // Phase 1: per channel, lane-contiguous float4 read (1KB/instr), bf16
    // pack, ds_write_b64 (8B/lane -> ~4-way bank alias, negligible).
#pragma unroll
    for (int c = 0; c < NC; ++c) {
        float4 v = *reinterpret_cast<const float4*>(
            src + (size_t)c * FSZ + tid * 4);
        uint2 p;
        p.x = (unsigned int)f2bf_rne(v.x) | ((unsigned int)f2bf_rne(v.y) << 16);
        p.y = (unsigned int)f2bf_rne(v.z) | ((unsigned int)f2bf_rne(v.w) << 16);
        *reinterpret_cast<uint2*>(&lds[c * TR_TILE + tid * 4]) = p;
    }
    __syncthreads();

    // Phase 2: lane writes out bytes s*4096 + tid*16 (consecutive lanes ->
    // consecutive 16B; 1KB contiguous per wave store instruction).
    unsigned short* dstu = ft + ((size_t)btn * FSZ + base) * NC;
    int half = tid & 1;        // which 8-channel half of the row
    int prow = tid >> 1;       // 0..127
#pragma unroll
    for (int s = 0; s < 8; ++s) {
        int p = s * 128 + prow;
        unsigned int w[4];
#pragma unroll
        for (int jj = 0; jj < 4; ++jj) {
            unsigned short a = lds[(half * 8 + 2 * jj) * TR_TILE + p];
            unsigned short b2 = lds[(half * 8 + 2 * jj + 1) * TR_TILE + p];
            w[jj] = (unsigned int)a | ((unsigned int)b2 << 16);
        }
        *reinterpret_cast<uint4*>(dstu + (size_t)p * NC + half * 8) =
            make_uint4(w[0], w[1], w[2], w[3]);
    }
}

// ----------------------------------------------------------------------------
// Kernel 1: frustum trilinear sample (6 cams x 16 ch) + W_N matvec + ReLU,
// + hoisted W_T-block matvec: store g_t = W_T[:, t*40:] @ relu(h)  (bf16).
// bf16 ft gather (2 x uint4 = 32B/corner). Per-cam validity early-out.
// Light-thread shortcut: no valid cam -> constant g row from setup.
// Unchanged from R8.
// ----------------------------------------------------------------------------
template <bool CHLAST>
__global__ __launch_bounds__(256) void sample_mlp1(
    const float* __restrict__ feat,            // original layout (!CHLAST)
    const unsigned short* __restrict__ ft,     // bf16 channel-last (CHLAST)
    const float* __restrict__ P,
    const float* __restrict__ W_N,
    const float* __restrict__ b_N,
    const float* __restrict__ W_T,
    const unsigned short* __restrict__ g_const,
    unsigned short* __restrict__ g) {
    int tid = blockIdx.x * 256 + threadIdx.x;
    int vid = tid % NVOX;
    int bt = __builtin_amdgcn_readfirstlane(tid / NVOX);  // wave-uniform (NVOX%64==0)
    int gy = vid % GY;
    int r2 = vid / GY;
    int gz = r2 % GZ;
    int gx = r2 / GZ;
    float X = (float)gx - 49.5f;
    float Y = (float)gy - 49.5f;
    float Z = (float)gz - 2.5f;

    uint4* d4 = reinterpret_cast<uint4*>(
        g + ((size_t)bt * NVOX + (size_t)vid) * OC);

    float acc[OC];
#pragma unroll
    for (int o = 0; o < OC; ++o) acc[o] = b_N[o];

    bool any_valid = false;

    for (int n = 0; n < NCAM; ++n) {
        const float* Pp = P + (bt * NCAM + n) * 12;
        float px = Pp[0] * X + Pp[1] * Y + Pp[2] * Z + Pp[3];
        float py = Pp[4] * X + Pp[5] * Y + Pp[6] * Z + Pp[7];
        float pz = Pp[8] * X + Pp[9] * Y + Pp[10] * Z + Pp[11];
        float zc = fmaxf(pz, 1e-5f);
        float ix = px / zc;                       // = u (normalization round-trips)
        float iy = py / zc;
        float iz = (pz - 2.0f) * (48.0f / 44.8f); // = dbin

        // exact early-out: outside the open box, every corner weight is zero
        bool cam_valid = (ix > -1.f) & (ix < (float)FW) &
                         (iy > -1.f) & (iy < (float)FH) &
                         (iz > -1.f) & (iz < (float)FD);
        if (!cam_valid) continue;
        any_valid = true;

        float x0 = floorf(ix), y0 = floorf(iy), z0 = floorf(iz);
        float wx1 = ix - x0, wy1 = iy - y0, wz1 = iz - z0;
        float wx0 = 1.f - wx1, wy0 = 1.f - wy1, wz0 = 1.f - wz1;

        float w8[8];
        int off8[8];
#pragma unroll
        for (int k = 0; k < 8; ++k) {
            float xf = x0 + (float)(k & 1);
            float yf = y0 + (float)((k >> 1) & 1);
            float zf = z0 + (float)(k >> 2);
            bool valid = (xf >= 0.f) & (xf <= (float)(FW - 1)) &
                         (yf >= 0.f) & (yf <= (float)(FH - 1)) &
                         (zf >= 0.f) & (zf <= (float)(FD - 1));
            int xi = (int)fminf(fmaxf(xf, 0.f), (float)(FW - 1));
            int yi = (int)fminf(fmaxf(yf, 0.f), (float)(FH - 1));
            int zi = (int)fminf(fmaxf(zf, 0.f), (float)(FD - 1));
            float w = ((k & 1) ? wx1 : wx0) * (((k >> 1) & 1) ? wy1 : wy0) *
                      ((k >> 2) ? wz1 : wz0);
            w8[k] = valid ? w : 0.f;
            off8[k] = (zi * FH + yi) * FW + xi;
        }

        float s[NC];
#pragma unroll
        for (int c = 0; c < NC; ++c) s[c] = 0.f;

        if constexpr (CHLAST) {
            const size_t camBase = (size_t)(bt * NCAM + n) * FSZ;
#pragma unroll
            for (int k = 0; k < 8; ++k) {
                float w = w8[k];
                const uint4* cp = reinterpret_cast<const uint4*>(
                    ft + (camBase + (size_t)off8[k]) * NC);
                uint4 a = cp[0], b2 = cp[1];
                unsigned int uu[8] = {a.x, a.y, a.z, a.w, b2.x, b2.y, b2.z, b2.w};
#pragma unroll
                for (int j = 0; j < 8; ++j) {
                    s[2 * j + 0] = fmaf(w, bf_lo(uu[j]), s[2 * j + 0]);
                    s[2 * j + 1] = fmaf(w, bf_hi(uu[j]), s[2 * j + 1]);
                }
            }
        } else {
            const float* fn = feat + (size_t)bt * BTSZ + (size_t)n * CAMSZ;
#pragma unroll
            for (int c = 0; c < NC; ++c) {
                const float* fc = fn + (size_t)c * FSZ;
                float v = 0.f;
#pragma unroll
                for (int k = 0; k < 8; ++k) v = fmaf(w8[k], fc[off8[k]], v);
                s[c] = v;
            }
        }

        // acc[o] += W_N[o, n*16 + c] * s[c]
#pragma unroll
        for (int o = 0; o < OC; ++o) {
            const float4* w4 =
                reinterpret_cast<const float4*>(W_N + o * (NCAM * NC) + n * NC);
#pragma unroll
            for (int q = 0; q < 4; ++q) {
                float4 w = w4[q];
                acc[o] = fmaf(w.x, s[4 * q + 0], acc[o]);
                acc[o] = fmaf(w.y, s[4 * q + 1], acc[o]);
                acc[o] = fmaf(w.z, s[4 * q + 2], acc[o]);
                acc[o] = fmaf(w.w, s[4 * q + 3], acc[o]);
            }
        }
    }

    // ---- light-thread shortcut: no cam saw this voxel -> constant g row ----
    if (!any_valid) {
        const uint4* gc = reinterpret_cast<const uint4*>(
            g_const + (size_t)bt * OC);
        uint4 r0 = gc[0], r1 = gc[1], r2_ = gc[2], r3 = gc[3], r4 = gc[4];
        d4[0] = r0; d4[1] = r1; d4[2] = r2_; d4[3] = r3; d4[4] = r4;
        return;
    }

    // ReLU (this is h), then hoisted W_T-block matvec: g = W_T[:, t*40:] @ h.
    // 8 outputs at a time to keep the live set small (R4 spill lesson).
#pragma unroll
    for (int o = 0; o < OC; ++o) acc[o] = fmaxf(acc[o], 0.f);

    const int t = bt % NT;  // wave-uniform
    const float* Wtb = W_T + t * OC;            // row o at Wtb + o*(NT*OC)
#pragma unroll
    for (int grp = 0; grp < 5; ++grp) {
        float g8[8];
#pragma unroll
        for (int j = 0; j < 8; ++j) {
            const float4* w4 = reinterpret_cast<const float4*>(
                Wtb + (size_t)(grp * 8 + j) * (NT * OC));
            float s0 = 0.f;
#pragma unroll
            for (int q = 0; q < 10; ++q) {
                float4 w = w4[q];
                s0 = fmaf(w.x, acc[4 * q + 0], s0);
                s0 = fmaf(w.y, acc[4 * q + 1], s0);
                s0 = fmaf(w.z, acc[4 * q + 2], s0);
                s0 = fmaf(w.w, acc[4 * q + 3], s0);
            }
            g8[j] = s0;
        }
        unsigned int u0 = (unsigned int)f2bf_rne(g8[0]) |
                          ((unsigned int)f2bf_rne(g8[1]) << 16);
        unsigned int u1 = (unsigned int)f2bf_rne(g8[2]) |
                          ((unsigned int)f2bf_rne(g8[3]) << 16);
        unsigned int u2 = (unsigned int)f2bf_rne(g8[4]) |
                          ((unsigned int)f2bf_rne(g8[5]) << 16);
        unsigned int u3 = (unsigned int)f2bf_rne(g8[6]) |
                          ((unsigned int)f2bf_rne(g8[7]) << 16);
        d4[grp] = make_uint4(u0, u1, u2, u3);
    }
}

// ----------------------------------------------------------------------------
// Kernel 2: temporal warp, post-hoist: out = relu(gather_t0(g0) + gather_t1(g1)
// + g2[vid] + b_T). t=2 theta == I -> exact pass-through (single 80B load).
// Unchanged from R7. out layout: [b][o][d][h][w] = (B,40,100,8,100)
// ----------------------------------------------------------------------------
__global__ __launch_bounds__(256) void warp_mlp2(
    const unsigned short* __restrict__ g,
    const float* __restrict__ theta,
    const float* __restrict__ b_T,
    float* __restrict__ out) {
    int bid = xcd_swizzle(blockIdx.x, gridDim.x);
    int tid = bid * 256 + threadIdx.x;
    int vid = tid % NVOX;
    int b = __builtin_amdgcn_readfirstlane(tid / NVOX);  // wave-uniform
    int w_ = vid % GY;        // Wp = 100
    int r2 = vid / GY;
    int h_ = r2 % GZ;         // Hp = 8
    int d_ = r2 / GZ;         // Dp = 100

    float xg = -1.f + 2.f * (float)w_ / 99.f;
    float yg = -1.f + 2.f * (float)h_ / 7.f;
    float zg = -1.f + 2.f * (float)d_ / 99.f;

    float sval[OC];
#pragma unroll
    for (int o = 0; o < OC; ++o) sval[o] = b_T[o];

    // ---- t = 0, 1: trilinear gather of g_t, accumulated into sval ----
    for (int t = 0; t < 2; ++t) {
        const float* th = theta + (b * NT + t) * 12;
        float g0 = th[0] * xg + th[1] * yg + th[2] * zg + th[3];
        float g1 = th[4] * xg + th[5] * yg + th[6] * zg + th[7];
        float g2 = th[8] * xg + th[9] * yg + th[10] * zg + th[11];
        float ix = (g0 + 1.f) * 0.5f * 99.f;
        float iy = (g1 + 1.f) * 0.5f * 7.f;
        float iz = (g2 + 1.f) * 0.5f * 99.f;
        float x0 = floorf(ix), y0 = floorf(iy), z0 = floorf(iz);
        float wx1 = ix - x0, wy1 = iy - y0, wz1 = iz - z0;
        float wx0 = 1.f - wx1, wy0 = 1.f - wy1, wz0 = 1.f - wz1;

        float w8[8];
        int off8[8];
#pragma unroll
        for (int k = 0; k < 8; ++k) {
            float xf = x0 + (float)(k & 1);
            float yf = y0 + (float)((k >> 1) & 1);
            float zf = z0 + (float)(k >> 2);
            bool valid = (xf >= 0.f) & (xf <= 99.f) &
                         (yf >= 0.f) & (yf <= 7.f) &
                         (zf >= 0.f) & (zf <= 99.f);
            int xi = (int)fminf(fmaxf(xf, 0.f), 99.f);
            int yi = (int)fminf(fmaxf(yf, 0.f), 7.f);
            int zi = (int)fminf(fmaxf(zf, 0.f), 99.f);
            float w = ((k & 1) ? wx1 : wx0) * (((k >> 1) & 1) ? wy1 : wy0) *
                      ((k >> 2) ? wz1 : wz0);
            w8[k] = valid ? w : 0.f;
            off8[k] = (zi * GZ + yi) * GY + xi;  // voxel index in [vid] space
        }

        const unsigned short* hb = g + (size_t)(b * NT + t) * NVOX * OC;
#pragma unroll
        for (int k = 0; k < 8; ++k) {
            float w = w8[k];
            const uint4* cp =
                reinterpret_cast<const uint4*>(hb + (size_t)off8[k] * OC);
            uint4 a0 = cp[0], a1 = cp[1], a2 = cp[2], a3 = cp[3], a4 = cp[4];
            unsigned int uu[20] = {a0.x, a0.y, a0.z, a0.w, a1.x, a1.y, a1.z, a1.w,
                                   a2.x, a2.y, a2.z, a2.w, a3.x, a3.y, a3.z, a3.w,
                                   a4.x, a4.y, a4.z, a4.w};
#pragma unroll
            for (int j = 0; j < 20; ++j) {
                sval[2 * j + 0] = fmaf(w, bf_lo(uu[j]), sval[2 * j + 0]);
                sval[2 * j + 1] = fmaf(w, bf_hi(uu[j]), sval[2 * j + 1]);
            }
        }
    }

    // ---- t = 2: identity grid -> exact pass-through (single 80B load) ----
    {
        const uint4* cp = reinterpret_cast<const uint4*>(
            g + ((size_t)(b * NT + 2) * NVOX + (size_t)vid) * OC);
        uint4 a0 = cp[0], a1 = cp[1], a2 = cp[2], a3 = cp[3], a4 = cp[4];
        unsigned int uu[20] = {a0.x, a0.y, a0.z, a0.w, a1.x, a1.y, a1.z, a1.w,
                               a2.x, a2.y, a2.z, a2.w, a3.x, a3.y, a3.z, a3.w,
                               a4.x, a4.y, a4.z, a4.w};
#pragma unroll
        for (int j = 0; j < 20; ++j) {
            sval[2 * j + 0] += bf_lo(uu[j]);
            sval[2 * j + 1] += bf_hi(uu[j]);
        }
    }

    // per-o planes: lanes have consecutive vid -> coalesced per o
    float* op = out + (size_t)b * OC * NVOX + vid;
#pragma unroll
    for (int o = 0; o < OC; ++o) op[(size_t)o * NVOX] = fmaxf(sval[o], 0.f);
}

extern "C" void kernel_launch(void* const* d_in, const int* in_sizes, int n_in,
                              void* d_out, int out_size, void* d_ws, size_t ws_size,
                              hipStream_t stream) {
    const float* frustum = (const float*)d_in[0];
    const float* RT      = (const float*)d_in[1];
    const float* intrins = (const float*)d_in[2];
    const float* DoF     = (const float*)d_in[3];
    const float* W_N     = (const float*)d_in[4];
    const float* b_N     = (const float*)d_in[5];
    const float* W_T     = (const float*)d_in[6];
    const float* b_T     = (const float*)d_in[7];
    float* out = (float*)d_out;

    const size_t ft_bytes = FT_ELEMS * sizeof(unsigned short); // ~85 MB
    const size_t g_bytes  = HSZ * sizeof(unsigned short);      // ~38.4 MB
    const size_t small = 4096;                                 // P + theta + g_const

    char* base = (char*)d_ws;
    bool use_ft = ws_size >= ft_bytes + g_bytes + small;

    size_t ft_al = use_ft ? ((ft_bytes + 255) & ~(size_t)255) : 0;
    unsigned short* ft_buf = (unsigned short*)base;
    unsigned short* g_buf = (unsigned short*)(base + ft_al);
    float* P_buf = (float*)(base + ft_al + ((g_bytes + 255) & ~(size_t)255));
    float* th_buf = P_buf + NB * NT * NCAM * 12;              // 432 floats in
    unsigned short* gc_buf = (unsigned short*)(th_buf + NB * NT * 12);

    const int tr_blocks = NB * NT * NCAM * (FSZ / TR_TILE);  // 36*72 = 2592
    const int n1_blocks = (NB * NT * NVOX) / 256;            // 1875
    const int n2_blocks = (NB * NVOX) / 256;                 // 625

    if (use_ft) {
        transpose_feat<<<tr_blocks, 256, 0, stream>>>(
            frustum, ft_buf, RT, intrins, DoF, W_T, b_N, P_buf, th_buf, gc_buf);
        sample_mlp1<true><<<n1_blocks, 256, 0, stream>>>(
            frustum, ft_buf, P_buf, W_N, b_N, W_T, gc_buf, g_buf);
    } else {
        setup_kernel<<<1, 128, 0, stream>>>(
            RT, intrins, DoF, W_T, b_N, P_buf, th_buf, gc_buf);
        sample_mlp1<false><<<n1_blocks, 256, 0, stream>>>(
            frustum, (const unsigned short*)nullptr, P_buf, W_N, b_N, W_T,
            gc_buf, g_buf);
    }

    warp_mlp2<<<n2_blocks, 256, 0, stream>>>(g_buf, th_buf, b_T, out);
}